// Round 2
// baseline (1502.840 us; speedup 1.0000x reference)
//
#include <hip/hip_runtime.h>
#include <cstdint>

#define BB 2048
#define NN 128
#define DD 128
#define CHUNK 512

// ---------------- threefry2x32 (JAX-exact) ----------------
__device__ __forceinline__ void tf_round(uint32_t& x0, uint32_t& x1, int r) {
  x0 += x1; x1 = (x1 << r) | (x1 >> (32 - r)); x1 ^= x0;
}

__device__ __forceinline__ uint2 threefry(uint32_t k0, uint32_t k1, uint32_t x0, uint32_t x1) {
  uint32_t k2 = k0 ^ k1 ^ 0x1BD11BDAu;
  x0 += k0; x1 += k1;
  tf_round(x0,x1,13); tf_round(x0,x1,15); tf_round(x0,x1,26); tf_round(x0,x1,6);
  x0 += k1; x1 += k2 + 1u;
  tf_round(x0,x1,17); tf_round(x0,x1,29); tf_round(x0,x1,16); tf_round(x0,x1,24);
  x0 += k2; x1 += k0 + 2u;
  tf_round(x0,x1,13); tf_round(x0,x1,15); tf_round(x0,x1,26); tf_round(x0,x1,6);
  x0 += k0; x1 += k1 + 3u;
  tf_round(x0,x1,17); tf_round(x0,x1,29); tf_round(x0,x1,16); tf_round(x0,x1,24);
  x0 += k1; x1 += k2 + 4u;
  tf_round(x0,x1,13); tf_round(x0,x1,15); tf_round(x0,x1,26); tf_round(x0,x1,6);
  x0 += k2; x1 += k0 + 5u;
  uint2 r; r.x = x0; r.y = x1; return r;
}

__device__ __forceinline__ float gumbel_from_bits(uint32_t bits) {
  const float TINY = 1.17549435e-38f;
  float u = __uint_as_float(0x3F800000u | (bits >> 9)) - 1.0f;   // [0,1)
  u = u + TINY;
  u = fmaxf(TINY, u);
  return -logf(-logf(u));
}

// step keys: keys[i] = threefry((0,42),(0,i))  [partitionable split of key(42)]
__global__ void k_keys(uint2* __restrict__ keys) {
  int i = threadIdx.x;
  if (i < NN) keys[i] = threefry(0u, 42u, 0u, (uint32_t)i);  // fill 128 (last unused, safe prefetch)
}

// M = Wc2 @ Wq   (Wc rows 128..255 are the h_cur part)
__global__ void k_M(const float* __restrict__ Wc, const float* __restrict__ Wq,
                    float* __restrict__ M) {
  __shared__ __align__(16) float wrow[DD];
  int r = blockIdx.x, o = threadIdx.x;
  wrow[o] = Wc[(DD + r) * DD + o];
  __syncthreads();
  float acc = 0.f;
#pragma unroll 4
  for (int c = 0; c < DD; ++c) acc += wrow[c] * Wq[c * DD + o];
  M[r * DD + o] = acc;
}

// Qbase[b] = (graph[b]@Wc1 + bc) @ Wq + bq
__global__ void k_qbase(const float* __restrict__ graph, const float* __restrict__ Wc,
                        const float* __restrict__ bc, const float* __restrict__ Wq,
                        const float* __restrict__ bq, float* __restrict__ Qbase) {
  __shared__ __align__(16) float g[DD];
  __shared__ __align__(16) float c1[DD];
  int b = blockIdx.x, t = threadIdx.x;
  g[t] = graph[b * DD + t];
  __syncthreads();
  float acc = 0.f;
#pragma unroll 4
  for (int r = 0; r < DD; ++r) acc += g[r] * Wc[r * DD + t];
  c1[t] = acc + bc[t];
  __syncthreads();
  float acc2 = 0.f;
#pragma unroll 4
  for (int c = 0; c < DD; ++c) acc2 += c1[c] * Wq[c * DD + t];
  Qbase[b * DD + t] = acc2 + bq[t];
}

// K = h@Wk + bk ; QQ = h@M + Qbase[b]   (64 rows per block, chunk-local outputs)
__global__ __launch_bounds__(256) void k_kqq(
    const float* __restrict__ h, const float* __restrict__ Wk, const float* __restrict__ bk,
    const float* __restrict__ Mm, const float* __restrict__ Qbase,
    float* __restrict__ Kc, float* __restrict__ QQc, int b0) {
  __shared__ __align__(16) float As[64 * DD];
  int tid = threadIdx.x;
  int grow0 = b0 * NN + blockIdx.x * 64;  // global flat row (b*N+n)
  for (int t = tid * 4; t < 64 * DD; t += 1024) {
    int r = t >> 7, k = t & 127;
    *(float4*)&As[t] = *(const float4*)&h[(grow0 + r) * DD + k];
  }
  __syncthreads();
  int ty = tid >> 5, tx = tid & 31;
  float accK[8][4] = {{0}}, accQ[8][4] = {{0}};
  for (int k4 = 0; k4 < DD; k4 += 4) {
    float4 a4[8];
#pragma unroll
    for (int i = 0; i < 8; ++i) a4[i] = *(const float4*)&As[(ty * 8 + i) * DD + k4];
#pragma unroll
    for (int kk = 0; kk < 4; ++kk) {
      float4 w = *(const float4*)&Wk[(k4 + kk) * DD + tx * 4];
      float4 m = *(const float4*)&Mm[(k4 + kk) * DD + tx * 4];
#pragma unroll
      for (int i = 0; i < 8; ++i) {
        float a = ((const float*)&a4[i])[kk];
        accK[i][0] += a * w.x; accK[i][1] += a * w.y; accK[i][2] += a * w.z; accK[i][3] += a * w.w;
        accQ[i][0] += a * m.x; accQ[i][1] += a * m.y; accQ[i][2] += a * m.z; accQ[i][3] += a * m.w;
      }
    }
  }
  float4 bk4 = *(const float4*)&bk[tx * 4];
#pragma unroll
  for (int i = 0; i < 8; ++i) {
    int grow = grow0 + ty * 8 + i;
    int b = grow >> 7;                 // global batch
    int lrow = grow - b0 * NN;         // chunk-local row
    float4 qb = *(const float4*)&Qbase[b * DD + tx * 4];
    float4 ok, oq;
    ok.x = accK[i][0] + bk4.x; ok.y = accK[i][1] + bk4.y;
    ok.z = accK[i][2] + bk4.z; ok.w = accK[i][3] + bk4.w;
    oq.x = accQ[i][0] + qb.x;  oq.y = accQ[i][1] + qb.y;
    oq.z = accQ[i][2] + qb.z;  oq.w = accQ[i][3] + qb.w;
    *(float4*)&Kc[lrow * DD + tx * 4] = ok;
    *(float4*)&QQc[lrow * DD + tx * 4] = oq;
  }
}

// T[b] = 10*tanh( QQ[b] @ K[b]^T / 32 ) — one block per b, 256 thr, 8x8 tiles,
// XOR-swizzled LDS (conflict-free a/b loads), k-panels of 32.
#define SW 36
__global__ __launch_bounds__(256) void k_score(
    const float* __restrict__ QQc, const float* __restrict__ Kc,
    float* __restrict__ T, int b0) {
  __shared__ __align__(16) float QQs[NN * SW];  // 18.4 KB
  __shared__ __align__(16) float Ks[NN * SW];   // 18.4 KB
  int bb = blockIdx.x;
  int tid = threadIdx.x;
  int ty = tid >> 4, tx = tid & 15;   // i0 = ty*8, n0 = tx*8
  const float* QQb = QQc + (size_t)bb * NN * DD;
  const float* Kb  = Kc  + (size_t)bb * NN * DD;
  float acc[8][8] = {{0}};
  for (int kp = 0; kp < DD; kp += 32) {
#pragma unroll
    for (int p = 0; p < 4; ++p) {
      int idx = tid + p * 256;            // 0..1023
      int row = idx >> 3, c4 = (idx & 7) * 4;
      int pc = c4 ^ (((row >> 3) & 7) * 4);
      *(float4*)&QQs[row * SW + pc] = *(const float4*)&QQb[row * DD + kp + c4];
      *(float4*)&Ks [row * SW + pc] = *(const float4*)&Kb [row * DD + kp + c4];
    }
    __syncthreads();
#pragma unroll
    for (int k4 = 0; k4 < 32; k4 += 4) {
      int ca = k4 ^ ((ty & 7) * 4);
      int cb = k4 ^ ((tx & 7) * 4);
      float4 a[8], bv[8];
#pragma unroll
      for (int i = 0; i < 8; ++i) a[i]  = *(const float4*)&QQs[(ty * 8 + i) * SW + ca];
#pragma unroll
      for (int j = 0; j < 8; ++j) bv[j] = *(const float4*)&Ks [(tx * 8 + j) * SW + cb];
#pragma unroll
      for (int i = 0; i < 8; ++i)
#pragma unroll
        for (int j = 0; j < 8; ++j)
          acc[i][j] += a[i].x * bv[j].x + a[i].y * bv[j].y +
                       a[i].z * bv[j].z + a[i].w * bv[j].w;
    }
    __syncthreads();
  }
  int b = b0 + bb;
#pragma unroll
  for (int i = 0; i < 8; ++i) {
    int row = ty * 8 + i;
    float4 o0, o1;
    o0.x = 10.0f * tanhf(acc[i][0] * 0.03125f);
    o0.y = 10.0f * tanhf(acc[i][1] * 0.03125f);
    o0.z = 10.0f * tanhf(acc[i][2] * 0.03125f);
    o0.w = 10.0f * tanhf(acc[i][3] * 0.03125f);
    o1.x = 10.0f * tanhf(acc[i][4] * 0.03125f);
    o1.y = 10.0f * tanhf(acc[i][5] * 0.03125f);
    o1.z = 10.0f * tanhf(acc[i][6] * 0.03125f);
    o1.w = 10.0f * tanhf(acc[i][7] * 0.03125f);
    float* dst = &T[((size_t)b * NN + row) * NN + tx * 8];
    *(float4*)dst = o0;
    *(float4*)(dst + 4) = o1;
  }
}

// sequential sampling: block per b; T[b] cached in LDS (64 KB); chain on wave 0.
// lane owns nodes (2*lane, 2*lane+1) -> row read is one ds_read_b64.
__global__ __launch_bounds__(256) void k_decode(
    const float* __restrict__ T, const uint2* __restrict__ keys, float* __restrict__ out) {
  __shared__ float Ts[NN * NN];   // 65536 B
  int b = blockIdx.x;
  int tid = threadIdx.x;
  const float4* src = (const float4*)(T + (size_t)b * NN * NN);
  float4* dst = (float4*)Ts;
#pragma unroll
  for (int i = 0; i < NN * NN / 4 / 256; ++i) dst[tid + i * 256] = src[tid + i * 256];
  __syncthreads();
  if (tid >= 64) return;
  int lane = tid;
  const int n0 = 2 * lane, n1 = 2 * lane + 1;
  bool vis0 = (n0 == 0), vis1 = false;
  float logp = 0.f;
  int cur = 0;
  if (lane == 0) out[b * NN] = 0.0f;
  uint2 knext = keys[0];
  for (int s = 0; s < NN - 1; ++s) {
    uint2 k = knext;
    knext = keys[s + 1];          // prefetch (keys buffer has 128 entries)
    float2 sc = *(const float2*)&Ts[cur * NN + n0];
    uint2 r0 = threefry(k.x, k.y, 0u, (uint32_t)(b * NN + n0));
    uint2 r1 = threefry(k.x, k.y, 0u, (uint32_t)(b * NN + n1));
    float g0 = gumbel_from_bits(r0.x ^ r0.y);
    float g1 = gumbel_from_bits(r1.x ^ r1.y);
    float v0 = vis0 ? -INFINITY : sc.x + g0;
    float v1 = vis1 ? -INFINITY : sc.y + g1;
    float bvv; int bi;
    if (v1 > v0) { bvv = v1; bi = n1; } else { bvv = v0; bi = n0; }
#pragma unroll
    for (int off = 32; off > 0; off >>= 1) {
      float ov = __shfl_xor(bvv, off);
      int oi = __shfl_xor(bi, off);
      if (ov > bvv || (ov == bvv && oi < bi)) { bvv = ov; bi = oi; }
    }
    int nxt = bi;  // global argmax, first-index tie-break
    float m = fmaxf(vis0 ? -INFINITY : sc.x, vis1 ? -INFINITY : sc.y);
#pragma unroll
    for (int off = 32; off > 0; off >>= 1) m = fmaxf(m, __shfl_xor(m, off));
    float e = (vis0 ? 0.f : expf(sc.x - m)) + (vis1 ? 0.f : expf(sc.y - m));
#pragma unroll
    for (int off = 32; off > 0; off >>= 1) e += __shfl_xor(e, off);
    float scn = Ts[cur * NN + nxt];
    logp += scn - m - logf(e);
    vis0 = vis0 || (n0 == nxt);
    vis1 = vis1 || (n1 == nxt);
    cur = nxt;
    if (lane == 0) out[b * NN + s + 1] = (float)nxt;
  }
  if (lane == 0) out[BB * NN + b] = logp;
}

extern "C" void kernel_launch(void* const* d_in, const int* in_sizes, int n_in,
                              void* d_out, int out_size, void* d_ws, size_t ws_size,
                              hipStream_t stream) {
  const float* h     = (const float*)d_in[0];
  const float* graph = (const float*)d_in[1];
  const float* Wq    = (const float*)d_in[2];
  const float* bq    = (const float*)d_in[3];
  const float* Wk    = (const float*)d_in[4];
  const float* bk    = (const float*)d_in[5];
  const float* Wc    = (const float*)d_in[8];
  const float* bc    = (const float*)d_in[9];
  float* out = (float*)d_out;

  char* ws = (char*)d_ws;
  uint2* keys  = (uint2*)ws;                                   // 1 KB
  float* Mm    = (float*)(ws + 1024);                          // 64 KB
  float* Qbase = (float*)(ws + 1024 + 65536);                  // 1 MB
  size_t toff  = 1024 + 65536 + 1048576;
  float* T     = (float*)(ws + toff);                          // 134 MB
  size_t koff  = toff + (size_t)BB * NN * NN * 4;
  float* Kc    = (float*)(ws + koff);                          // 33.5 MB
  float* QQc   = (float*)(ws + koff + (size_t)CHUNK * NN * DD * 4); // 33.5 MB

  k_keys<<<1, 128, 0, stream>>>(keys);
  k_M<<<128, 128, 0, stream>>>(Wc, Wq, Mm);
  k_qbase<<<BB, 128, 0, stream>>>(graph, Wc, bc, Wq, bq, Qbase);
  for (int b0 = 0; b0 < BB; b0 += CHUNK) {
    k_kqq<<<CHUNK * NN / 64, 256, 0, stream>>>(h, Wk, bk, Mm, Qbase, Kc, QQc, b0);
    k_score<<<CHUNK, 256, 0, stream>>>(QQc, Kc, T, b0);
  }
  k_decode<<<BB, 256, 0, stream>>>(T, keys, out);
}

// Round 4
// 1103.947 us; speedup vs baseline: 1.3613x; 1.3613x over previous
//
#include <hip/hip_runtime.h>
#include <cstdint>

#define BB 2048
#define NN 128
#define DD 128
#define CHUNK 512
#define SW 36

// ---------------- threefry2x32 (JAX-exact) ----------------
__device__ __forceinline__ void tf_round(uint32_t& x0, uint32_t& x1, int r) {
  x0 += x1; x1 = (x1 << r) | (x1 >> (32 - r)); x1 ^= x0;
}

__device__ __forceinline__ uint2 threefry(uint32_t k0, uint32_t k1, uint32_t x0, uint32_t x1) {
  uint32_t k2 = k0 ^ k1 ^ 0x1BD11BDAu;
  x0 += k0; x1 += k1;
  tf_round(x0,x1,13); tf_round(x0,x1,15); tf_round(x0,x1,26); tf_round(x0,x1,6);
  x0 += k1; x1 += k2 + 1u;
  tf_round(x0,x1,17); tf_round(x0,x1,29); tf_round(x0,x1,16); tf_round(x0,x1,24);
  x0 += k2; x1 += k0 + 2u;
  tf_round(x0,x1,13); tf_round(x0,x1,15); tf_round(x0,x1,26); tf_round(x0,x1,6);
  x0 += k0; x1 += k1 + 3u;
  tf_round(x0,x1,17); tf_round(x0,x1,29); tf_round(x0,x1,16); tf_round(x0,x1,24);
  x0 += k1; x1 += k2 + 4u;
  tf_round(x0,x1,13); tf_round(x0,x1,15); tf_round(x0,x1,26); tf_round(x0,x1,6);
  x0 += k2; x1 += k0 + 5u;
  uint2 r; r.x = x0; r.y = x1; return r;
}

__device__ __forceinline__ float gumbel_from_bits(uint32_t bits) {
  const float TINY = 1.17549435e-38f;
  float u = __uint_as_float(0x3F800000u | (bits >> 9)) - 1.0f;   // [0,1)
  u = u + TINY;
  u = fmaxf(TINY, u);
  return -logf(-logf(u));
}

// keys[i] = threefry((0,42),(0,i))  — 128 entries (last unused, safe prefetch)
__global__ void k_keys(uint2* __restrict__ keys) {
  int i = threadIdx.x;
  if (i < NN) keys[i] = threefry(0u, 42u, 0u, (uint32_t)i);
}

// M = Wc2 @ Wq   (Wc rows 128..255 are the h_cur part)
__global__ void k_M(const float* __restrict__ Wc, const float* __restrict__ Wq,
                    float* __restrict__ M) {
  __shared__ __align__(16) float wrow[DD];
  int r = blockIdx.x, o = threadIdx.x;
  wrow[o] = Wc[(DD + r) * DD + o];
  __syncthreads();
  float acc = 0.f;
#pragma unroll 4
  for (int c = 0; c < DD; ++c) acc += wrow[c] * Wq[c * DD + o];
  M[r * DD + o] = acc;
}

// Qbase[b] = (graph[b]@Wc1 + bc) @ Wq + bq
__global__ void k_qbase(const float* __restrict__ graph, const float* __restrict__ Wc,
                        const float* __restrict__ bc, const float* __restrict__ Wq,
                        const float* __restrict__ bq, float* __restrict__ Qbase) {
  __shared__ __align__(16) float g[DD];
  __shared__ __align__(16) float c1[DD];
  int b = blockIdx.x, t = threadIdx.x;
  g[t] = graph[b * DD + t];
  __syncthreads();
  float acc = 0.f;
#pragma unroll 4
  for (int r = 0; r < DD; ++r) acc += g[r] * Wc[r * DD + t];
  c1[t] = acc + bc[t];
  __syncthreads();
  float acc2 = 0.f;
#pragma unroll 4
  for (int c = 0; c < DD; ++c) acc2 += c1[c] * Wq[c * DD + t];
  Qbase[b * DD + t] = acc2 + bq[t];
}

// K = h@Wk + bk ; QQ = h@M + Qbase[b]   (64 rows per block, chunk-local outputs)
__global__ __launch_bounds__(256) void k_kqq(
    const float* __restrict__ h, const float* __restrict__ Wk, const float* __restrict__ bk,
    const float* __restrict__ Mm, const float* __restrict__ Qbase,
    float* __restrict__ Kc, float* __restrict__ QQc, int b0) {
  __shared__ __align__(16) float As[64 * DD];
  int tid = threadIdx.x;
  int grow0 = b0 * NN + blockIdx.x * 64;  // global flat row (b*N+n)
  for (int t = tid * 4; t < 64 * DD; t += 1024) {
    int r = t >> 7, k = t & 127;
    *(float4*)&As[t] = *(const float4*)&h[(grow0 + r) * DD + k];
  }
  __syncthreads();
  int ty = tid >> 5, tx = tid & 31;
  float accK[8][4] = {{0}}, accQ[8][4] = {{0}};
  for (int k4 = 0; k4 < DD; k4 += 4) {
    float4 a4[8];
#pragma unroll
    for (int i = 0; i < 8; ++i) a4[i] = *(const float4*)&As[(ty * 8 + i) * DD + k4];
#pragma unroll
    for (int kk = 0; kk < 4; ++kk) {
      float4 w = *(const float4*)&Wk[(k4 + kk) * DD + tx * 4];
      float4 m = *(const float4*)&Mm[(k4 + kk) * DD + tx * 4];
#pragma unroll
      for (int i = 0; i < 8; ++i) {
        float a = ((const float*)&a4[i])[kk];
        accK[i][0] += a * w.x; accK[i][1] += a * w.y; accK[i][2] += a * w.z; accK[i][3] += a * w.w;
        accQ[i][0] += a * m.x; accQ[i][1] += a * m.y; accQ[i][2] += a * m.z; accQ[i][3] += a * m.w;
      }
    }
  }
  float4 bk4 = *(const float4*)&bk[tx * 4];
#pragma unroll
  for (int i = 0; i < 8; ++i) {
    int grow = grow0 + ty * 8 + i;
    int b = grow >> 7;                 // global batch
    int lrow = grow - b0 * NN;         // chunk-local row
    float4 qb = *(const float4*)&Qbase[b * DD + tx * 4];
    float4 ok, oq;
    ok.x = accK[i][0] + bk4.x; ok.y = accK[i][1] + bk4.y;
    ok.z = accK[i][2] + bk4.z; ok.w = accK[i][3] + bk4.w;
    oq.x = accQ[i][0] + qb.x;  oq.y = accQ[i][1] + qb.y;
    oq.z = accQ[i][2] + qb.z;  oq.w = accQ[i][3] + qb.w;
    *(float4*)&Kc[lrow * DD + tx * 4] = ok;
    *(float4*)&QQc[lrow * DD + tx * 4] = oq;
  }
}

// T[b] = 10*tanh( QQ[b] @ K[b]^T / 32 ) — one block per b, 256 thr, 8x8 tiles,
// XOR-swizzled LDS, k-panels of 32.  (bit-identical to R2's passing k_score)
__global__ __launch_bounds__(256) void k_score(
    const float* __restrict__ QQc, const float* __restrict__ Kc,
    float* __restrict__ T, int b0) {
  __shared__ __align__(16) float QQs[NN * SW];
  __shared__ __align__(16) float Ks[NN * SW];
  int bb = blockIdx.x;
  int tid = threadIdx.x;
  int ty = tid >> 4, tx = tid & 15;
  const float* QQb = QQc + (size_t)bb * NN * DD;
  const float* Kb  = Kc  + (size_t)bb * NN * DD;
  float acc[8][8] = {{0}};
  for (int kp = 0; kp < DD; kp += 32) {
#pragma unroll
    for (int p = 0; p < 4; ++p) {
      int idx = tid + p * 256;
      int row = idx >> 3, c4 = (idx & 7) * 4;
      int pc = c4 ^ (((row >> 3) & 7) * 4);
      *(float4*)&QQs[row * SW + pc] = *(const float4*)&QQb[row * DD + kp + c4];
      *(float4*)&Ks [row * SW + pc] = *(const float4*)&Kb [row * DD + kp + c4];
    }
    __syncthreads();
#pragma unroll
    for (int k4 = 0; k4 < 32; k4 += 4) {
      int ca = k4 ^ ((ty & 7) * 4);
      int cb = k4 ^ ((tx & 7) * 4);
      float4 a[8], bv[8];
#pragma unroll
      for (int i = 0; i < 8; ++i) a[i]  = *(const float4*)&QQs[(ty * 8 + i) * SW + ca];
#pragma unroll
      for (int j = 0; j < 8; ++j) bv[j] = *(const float4*)&Ks [(tx * 8 + j) * SW + cb];
#pragma unroll
      for (int i = 0; i < 8; ++i)
#pragma unroll
        for (int j = 0; j < 8; ++j)
          acc[i][j] += a[i].x * bv[j].x + a[i].y * bv[j].y +
                       a[i].z * bv[j].z + a[i].w * bv[j].w;
    }
    __syncthreads();
  }
  int b = b0 + bb;
#pragma unroll
  for (int i = 0; i < 8; ++i) {
    int row = ty * 8 + i;
    float4 o0, o1;
    o0.x = 10.0f * tanhf(acc[i][0] * 0.03125f);
    o0.y = 10.0f * tanhf(acc[i][1] * 0.03125f);
    o0.z = 10.0f * tanhf(acc[i][2] * 0.03125f);
    o0.w = 10.0f * tanhf(acc[i][3] * 0.03125f);
    o1.x = 10.0f * tanhf(acc[i][4] * 0.03125f);
    o1.y = 10.0f * tanhf(acc[i][5] * 0.03125f);
    o1.z = 10.0f * tanhf(acc[i][6] * 0.03125f);
    o1.w = 10.0f * tanhf(acc[i][7] * 0.03125f);
    float* dst = &T[((size_t)b * NN + row) * NN + tx * 8];
    *(float4*)dst = o0;
    *(float4*)(dst + 4) = o1;
  }
}

// chain-only decode: one wave per b; per step = dependent T-row read (float2) +
// in-loop threefry/gumbel (independent, overlaps the load) + ONE argmax butterfly.
// softmax/logp stripped out to k_logp.
__global__ __launch_bounds__(64) void k_decode(
    const float* __restrict__ T, const uint2* __restrict__ keys,
    float* __restrict__ out, int* __restrict__ pos) {
  __shared__ uint2 klds[NN];
  int b = blockIdx.x;
  int lane = threadIdx.x;
  klds[lane] = keys[lane];
  klds[lane + 64] = keys[lane + 64];
  __syncthreads();
  const int n0 = 2 * lane;
  bool vis0 = (n0 == 0), vis1 = false;
  int cur = 0;
  if (lane == 0) { out[b * NN] = 0.0f; pos[b * NN] = 0; }
  const float* Tb = T + (size_t)b * NN * NN;
  for (int s = 0; s < NN - 1; ++s) {
    uint2 k = klds[s];
    float2 sc = *(const float2*)&Tb[cur * NN + n0];      // dependent load
    uint2 r0 = threefry(k.x, k.y, 0u, (uint32_t)(b * NN + n0));     // independent:
    uint2 r1 = threefry(k.x, k.y, 0u, (uint32_t)(b * NN + n0 + 1)); // overlaps load
    float g0 = gumbel_from_bits(r0.x ^ r0.y);
    float g1 = gumbel_from_bits(r1.x ^ r1.y);
    float v0 = vis0 ? -INFINITY : sc.x + g0;
    float v1 = vis1 ? -INFINITY : sc.y + g1;
    float bvv; int bi;
    if (v1 > v0) { bvv = v1; bi = n0 + 1; } else { bvv = v0; bi = n0; }
#pragma unroll
    for (int off = 32; off > 0; off >>= 1) {
      float ov = __shfl_xor(bvv, off);
      int oi = __shfl_xor(bi, off);
      if (ov > bvv || (ov == bvv && oi < bi)) { bvv = ov; bi = oi; }
    }
    cur = bi;
    vis0 = vis0 || (n0 == cur);
    vis1 = vis1 || (n0 + 1 == cur);
    if (lane == 0) { out[b * NN + s + 1] = (float)cur; pos[b * NN + cur] = s + 1; }
  }
}

// fully parallel logp: block per b, thread s; T[b] staged in LDS; visited from pos
__global__ __launch_bounds__(128) void k_logp(
    const float* __restrict__ T, const int* __restrict__ pos,
    float* __restrict__ out) {
  __shared__ __align__(16) float Ts[NN * NN];   // 64 KB
  __shared__ int poss[NN];
  __shared__ float parts[NN];
  int b = blockIdx.x, tid = threadIdx.x;
  const float4* src = (const float4*)(T + (size_t)b * NN * NN);
  float4* dst = (float4*)Ts;
  for (int i = tid; i < NN * NN / 4; i += 128) dst[i] = src[i];
  poss[tid] = pos[b * NN + tid];
  __syncthreads();
  int s = tid;
  float lp = 0.f;
  if (s < NN - 1) {
    int r = 0;
    for (int n = 0; n < NN; ++n) if (poss[n] == s) r = n;   // cur at step s
    const float* row = &Ts[r * NN];
    float m = -INFINITY;
    for (int n = 0; n < NN; ++n) {
      if (poss[n] > s) m = fmaxf(m, row[n]);                 // unvisited at step s
    }
    float e = 0.f, scn = 0.f;
    for (int n = 0; n < NN; ++n) {
      float sc = row[n];
      if (poss[n] > s) e += expf(sc - m);
      if (poss[n] == s + 1) scn = sc;                        // chosen node
    }
    lp = scn - m - logf(e);
  }
  parts[tid] = lp;
  __syncthreads();
  if (tid == 0) {
    float acc = 0.f;
    for (int i = 0; i < NN - 1; ++i) acc += parts[i];
    out[BB * NN + b] = acc;
  }
}

extern "C" void kernel_launch(void* const* d_in, const int* in_sizes, int n_in,
                              void* d_out, int out_size, void* d_ws, size_t ws_size,
                              hipStream_t stream) {
  const float* h     = (const float*)d_in[0];
  const float* graph = (const float*)d_in[1];
  const float* Wq    = (const float*)d_in[2];
  const float* bq    = (const float*)d_in[3];
  const float* Wk    = (const float*)d_in[4];
  const float* bk    = (const float*)d_in[5];
  const float* Wc    = (const float*)d_in[8];
  const float* bc    = (const float*)d_in[9];
  float* out = (float*)d_out;

  char* ws = (char*)d_ws;
  uint2* keys  = (uint2*)ws;                        // 1 KB
  float* Mm    = (float*)(ws + 1024);               // 64 KB
  float* Qbase = (float*)(ws + 66560);              // 1 MB
  int*   pos   = (int*)  (ws + 1115136);            // 1 MB
  float* T     = (float*)(ws + (size_t)(4 << 20));  // 134.2 MB
  size_t koff  = (size_t)(4 << 20) + (size_t)BB * NN * NN * 4;
  float* Kc    = (float*)(ws + koff);                                   // 33.5 MB
  float* QQc   = (float*)(ws + koff + (size_t)CHUNK * NN * DD * 4);     // 33.5 MB

  k_keys<<<1, 128, 0, stream>>>(keys);
  k_M<<<128, 128, 0, stream>>>(Wc, Wq, Mm);
  k_qbase<<<BB, 128, 0, stream>>>(graph, Wc, bc, Wq, bq, Qbase);
  for (int b0 = 0; b0 < BB; b0 += CHUNK) {
    k_kqq<<<CHUNK * NN / 64, 256, 0, stream>>>(h, Wk, bk, Mm, Qbase, Kc, QQc, b0);
    k_score<<<CHUNK, 256, 0, stream>>>(QQc, Kc, T, b0);
  }
  k_decode<<<BB, 64, 0, stream>>>(T, keys, out, pos);
  k_logp<<<BB, 128, 0, stream>>>(T, pos, out);
}